// Round 5
// baseline (378.145 us; speedup 1.0000x reference)
//
#include <hip/hip_runtime.h>

// Problem constants
#define BS1 32
#define BS2 128
#define NEC 64
#define QD  256   // Q_DIM
#define MD  256   // MLP_DIM (== MEM_DIM)

// native vector type accepted by __builtin_nontemporal_store
typedef float nf4 __attribute__((ext_vector_type(4)));

// ---------------------------------------------------------------------------
// Prework (one launch, role-split by blockIdx):
//   blocks [0,256):   proj_c rows — proj_c[m,:] = crit_flat[m,:] @ Wm_c
//   blocks [256,272): proj_e rows — proj_e[m,:] = ehr[m,:] @ Wm_e
//   blocks [272,304): att[b,:]    — wave64 softmax of crit[b,e,:]·Wa_c
// (softmax is shift-invariant: logit_e[p] and b_align cancel over axis e)
// ---------------------------------------------------------------------------
__global__ __launch_bounds__(256)
void prework_kernel(const float* __restrict__ crit,
                    const float* __restrict__ ehr,
                    const float* __restrict__ w_align,
                    const float* __restrict__ w_mlp,
                    float* __restrict__ proj_c,
                    float* __restrict__ proj_e,
                    float* __restrict__ att) {
    __shared__ float As[8 * QD];   // 8 KB A tile (gemm roles)
    int blk = blockIdx.x;
    int tid = threadIdx.x;

    if (blk < 272) {
        // ---- GEMM role: 8 rows of A @ B(256x256) ----
        const float* A;
        const float* B;
        float*       O;
        int m0;
        if (blk < 256) { A = crit; B = w_mlp;           O = proj_c; m0 = blk * 8; }
        else           { A = ehr;  B = w_mlp + QD * MD; O = proj_e; m0 = (blk - 256) * 8; }
        {
            const float* src = A + m0 * QD + tid * 8;
            float4 a0 = *(const float4*)src;
            float4 a1 = *(const float4*)(src + 4);
            *(float4*)&As[tid * 8]     = a0;
            *(float4*)&As[tid * 8 + 4] = a1;
        }
        __syncthreads();
        int r = tid >> 5;           // row in [0,8)
        int c = (tid & 31) * 8;     // col base
        float acc[8] = {0.f,0.f,0.f,0.f,0.f,0.f,0.f,0.f};
        #pragma unroll 4
        for (int k = 0; k < QD; ++k) {
            float a = As[r * QD + k];
            const float* bp = B + k * MD + c;
            float4 b0 = *(const float4*)bp;
            float4 b1 = *(const float4*)(bp + 4);
            acc[0] = fmaf(a, b0.x, acc[0]);
            acc[1] = fmaf(a, b0.y, acc[1]);
            acc[2] = fmaf(a, b0.z, acc[2]);
            acc[3] = fmaf(a, b0.w, acc[3]);
            acc[4] = fmaf(a, b1.x, acc[4]);
            acc[5] = fmaf(a, b1.y, acc[5]);
            acc[6] = fmaf(a, b1.z, acc[6]);
            acc[7] = fmaf(a, b1.w, acc[7]);
        }
        float* o = O + (m0 + r) * MD + c;
        *(float4*)o       = make_float4(acc[0], acc[1], acc[2], acc[3]);
        *(float4*)(o + 4) = make_float4(acc[4], acc[5], acc[6], acc[7]);
    } else {
        // ---- att role: one wave (lanes 0-63), no barriers used ----
        if (tid >= 64) return;
        int b = blk - 272;
        int e = tid;
        const float* row = crit + (b * NEC + e) * QD;
        float acc = 0.f;
        for (int k = 0; k < QD; k += 4) {
            float4 u = *(const float4*)(row + k);   // per-lane row data
            // w_align[k..k+3] is wave-uniform -> scalar loads, L1-resident
            acc = fmaf(u.x, w_align[k + 0], acc);
            acc = fmaf(u.y, w_align[k + 1], acc);
            acc = fmaf(u.z, w_align[k + 2], acc);
            acc = fmaf(u.w, w_align[k + 3], acc);
        }
        float m = acc;
        #pragma unroll
        for (int off = 32; off; off >>= 1) m = fmaxf(m, __shfl_xor(m, off));
        float ex = __expf(acc - m);
        float s = ex;
        #pragma unroll
        for (int off = 32; off; off >>= 1) s += __shfl_xor(s, off);
        att[b * NEC + e] = ex / s;
    }
}

// ---------------------------------------------------------------------------
// h[b,p,e,d] = att[b,e] * (proj_c[b,e,d] + proj_e[p,d]) + b_mlp[d], fp32 out.
// One block per (b,p). d-slice (tid&31)*8 is pass-invariant: proj_e/b_mlp
// live in REGISTERS (no strided LDS -> zero bank conflicts). attb in LDS,
// read as 2-addr wave broadcast (free). Nontemporal streaming stores.
// ---------------------------------------------------------------------------
__global__ __launch_bounds__(256)
void final_kernel(const float* __restrict__ att,
                  const float* __restrict__ proj_c,
                  const float* __restrict__ proj_e,
                  const float* __restrict__ b_mlp,
                  float*       __restrict__ out) {
    __shared__ float attb[NEC];
    int tid = threadIdx.x;
    int bp  = blockIdx.x;
    int b = bp >> 7, p = bp & 127;
    int d = (tid & 31) * 8;        // pass-invariant column slice

    if (tid < NEC) attb[tid] = att[b * NEC + tid];

    // register-resident per-thread slices (coalesced 16B loads, L1/L2-hit)
    float4 e0 = *(const float4*)(proj_e + p * MD + d);
    float4 e1 = *(const float4*)(proj_e + p * MD + d + 4);
    float4 m0 = *(const float4*)(b_mlp + d);
    float4 m1 = *(const float4*)(b_mlp + d + 4);
    __syncthreads();

    const float* pc_base = proj_c + b * NEC * MD;
    float* out_base = out + (size_t)bp * (NEC * MD);
    #pragma unroll
    for (int pass = 0; pass < 8; ++pass) {
        int idx = pass * 256 + tid;
        int e = pass * 8 + (tid >> 5);           // [0,64)
        float a = attb[e];                       // 2 addrs/wave: free broadcast
        const float* pc = pc_base + e * MD + d;
        float4 c0 = *(const float4*)pc;
        float4 c1 = *(const float4*)(pc + 4);
        nf4 r0, r1;
        r0.x = fmaf(a, c0.x + e0.x, m0.x);
        r0.y = fmaf(a, c0.y + e0.y, m0.y);
        r0.z = fmaf(a, c0.z + e0.z, m0.z);
        r0.w = fmaf(a, c0.w + e0.w, m0.w);
        r1.x = fmaf(a, c1.x + e1.x, m1.x);
        r1.y = fmaf(a, c1.y + e1.y, m1.y);
        r1.z = fmaf(a, c1.z + e1.z, m1.z);
        r1.w = fmaf(a, c1.w + e1.w, m1.w);
        nf4* o = (nf4*)(out_base + (size_t)idx * 8);  // wave-contig 2 KiB
        __builtin_nontemporal_store(r0, o);
        __builtin_nontemporal_store(r1, o + 1);
    }
}

extern "C" void kernel_launch(void* const* d_in, const int* in_sizes, int n_in,
                              void* d_out, int out_size, void* d_ws, size_t ws_size,
                              hipStream_t stream) {
    // setup_inputs order: ehr_vector, criteria, ec_mask, W_align, b_align, W_mlp, b_mlp
    const float* ehr     = (const float*)d_in[0];   // (128, 256) fp32
    const float* crit    = (const float*)d_in[1];   // (32, 64, 256) fp32
    // d_in[2] ec_mask: all-ones, unused by reference
    const float* w_align = (const float*)d_in[3];   // (512,) -> use [:256]
    // d_in[4] b_align: cancels in softmax
    const float* w_mlp   = (const float*)d_in[5];   // (512, 256) row-major fp32
    const float* b_mlp   = (const float*)d_in[6];   // (256,)
    float* out = (float*)d_out;                      // (32,128,64,256) fp32

    // workspace layout (fp32): att[2048] | proj_c[2048*256] | proj_e[128*256]
    float* att    = (float*)d_ws;
    float* proj_c = att + BS1 * NEC;
    float* proj_e = proj_c + BS1 * NEC * MD;

    prework_kernel<<<272 + BS1, 256, 0, stream>>>(crit, ehr, w_align, w_mlp,
                                                  proj_c, proj_e, att);
    final_kernel<<<BS1 * BS2, 256, 0, stream>>>(att, proj_c, proj_e, b_mlp, out);
}